// Round 2
// baseline (1604.630 us; speedup 1.0000x reference)
//
#include <hip/hip_runtime.h>
#include <stdint.h>

typedef __attribute__((ext_vector_type(8))) short short8;
typedef __attribute__((ext_vector_type(4))) float f32x4;
typedef __attribute__((ext_vector_type(4))) unsigned short u16x4;

#define NTOK 8192
#define PDIM 16
#define ODIM 128

__device__ __forceinline__ uint16_t f2bf(float f) {
    uint32_t u = __builtin_bit_cast(uint32_t, f);
    u += 0x7FFFu + ((u >> 16) & 1u);   // RNE
    return (uint16_t)(u >> 16);
}

__global__ void convert_f32_bf16(const float* __restrict__ in, uint16_t* __restrict__ out, int n4) {
    int i = blockIdx.x * blockDim.x + threadIdx.x;
    if (i >= n4) return;
    f32x4 v = ((const f32x4*)in)[i];
    u16x4 o;
    o[0] = f2bf(v[0]); o[1] = f2bf(v[1]); o[2] = f2bf(v[2]); o[3] = f2bf(v[3]);
    ((u16x4*)out)[i] = o;
}

// C[m,n] = sum_k A[m,k] * B[n,k]  (B^T layout), bf16 in, fp32 accum.
// EPI 0: +bias, store bf16.  EPI 1: +bias, relu, store bf16.
// EPI 2: +bias, split mu/var, softplus on var, mask->NaN, store fp32 to out.
// Computed transposed (W rows feed the MFMA A-side) so each lane's 4 acc regs
// are contiguous in n -> vectorized epilogue stores.
template<int EPI>
__global__ __launch_bounds__(256)
void gemm_bt(const uint16_t* __restrict__ A, int lda, long long Abatch,
             const uint16_t* __restrict__ B, int ldb, long long Bbatch,
             const float* __restrict__ bias, int biasBatch,
             uint16_t* __restrict__ C, int ldc, long long Cbatch,
             int K,
             const unsigned char* __restrict__ mask,
             float* __restrict__ outv)
{
    __shared__ uint16_t As[128 * 64];
    __shared__ uint16_t Bs[128 * 64];

    const int tid  = threadIdx.x;
    const int wid  = tid >> 6;
    const int lane = tid & 63;
    const int m0 = blockIdx.x * 128;
    const int n0 = blockIdx.y * 128;
    const int p  = blockIdx.z;

    const uint16_t* Ap = A + (long long)p * Abatch;
    const uint16_t* Bp = B + (long long)p * Bbatch;
    const float* biasp = bias + (long long)p * biasBatch;

    // staging: each wave moves 32 rows/tile; lane -> (row = l>>3, col = (l&7)*8)
    const int srow = lane >> 3;
    const int scol = (lane & 7) * 8;
    const uint16_t* Ag = Ap + (long long)(m0 + wid * 32 + srow) * lda + scol;
    const uint16_t* Bg = Bp + (long long)(n0 + wid * 32 + srow) * ldb + scol;

    f32x4 acc[4][4];
    #pragma unroll
    for (int i = 0; i < 4; ++i)
        #pragma unroll
        for (int j = 0; j < 4; ++j)
            acc[i][j] = (f32x4){0.f, 0.f, 0.f, 0.f};

    const int wr = wid >> 1;   // m block (64)
    const int wc = wid & 1;    // n block (64)
    const int l15 = lane & 15;
    const int kg  = lane >> 4; // 0..3

    const int kTiles = K >> 6;
    for (int kt = 0; kt < kTiles; ++kt) {
        const int k0 = kt * 64;
        __syncthreads();  // previous compute done before overwrite
        #pragma unroll
        for (int i = 0; i < 4; ++i) {
            __builtin_amdgcn_global_load_lds(
                (const __attribute__((address_space(1))) void*)(Ag + (long long)i * 8 * lda + k0),
                (__attribute__((address_space(3))) void*)(&As[wid * 2048 + i * 512]),
                16, 0, 0);
            __builtin_amdgcn_global_load_lds(
                (const __attribute__((address_space(1))) void*)(Bg + (long long)i * 8 * ldb + k0),
                (__attribute__((address_space(3))) void*)(&Bs[wid * 2048 + i * 512]),
                16, 0, 0);
        }
        __syncthreads();  // compiler drains vmcnt before barrier

        #pragma unroll
        for (int ks = 0; ks < 2; ++ks) {
            const int kb = ks * 32 + kg * 8;
            short8 af[4], bfr[4];
            #pragma unroll
            for (int ni = 0; ni < 4; ++ni)
                af[ni] = *(const short8*)&Bs[(wc * 64 + ni * 16 + l15) * 64 + kb];
            #pragma unroll
            for (int mi = 0; mi < 4; ++mi)
                bfr[mi] = *(const short8*)&As[(wr * 64 + mi * 16 + l15) * 64 + kb];
            #pragma unroll
            for (int ni = 0; ni < 4; ++ni)
                #pragma unroll
                for (int mi = 0; mi < 4; ++mi)
                    acc[ni][mi] = __builtin_amdgcn_mfma_f32_16x16x32_bf16(af[ni], bfr[mi], acc[ni][mi], 0, 0, 0);
        }
    }

    // epilogue: D[n][m]; lane holds m = l15, n = base + kg*4 + j (j contiguous)
    if (EPI == 0 || EPI == 1) {
        uint16_t* Cp = C + (long long)p * Cbatch;
        #pragma unroll
        for (int ni = 0; ni < 4; ++ni) {
            const int gn = n0 + wc * 64 + ni * 16 + kg * 4;
            const f32x4 bv = *(const f32x4*)&biasp[gn];
            #pragma unroll
            for (int mi = 0; mi < 4; ++mi) {
                const int gm = m0 + wr * 64 + mi * 16 + l15;
                f32x4 v = acc[ni][mi];
                u16x4 o;
                #pragma unroll
                for (int j = 0; j < 4; ++j) {
                    float e = v[j] + bv[j];
                    if (EPI == 1) e = fmaxf(e, 0.f);
                    o[j] = f2bf(e);
                }
                *(u16x4*)&Cp[(long long)gm * ldc + gn] = o;
            }
        }
    } else {
        const long long VAROFF = (long long)NTOK * PDIM * ODIM;
        #pragma unroll
        for (int ni = 0; ni < 4; ++ni) {
            const int gn = n0 + wc * 64 + ni * 16 + kg * 4;
            const f32x4 bv = *(const f32x4*)&biasp[gn];
            #pragma unroll
            for (int mi = 0; mi < 4; ++mi) {
                const int gm = m0 + wr * 64 + mi * 16 + l15;     // local sample idx
                const long long token = (long long)gm * PDIM + p;
                const bool msk = mask[token] != 0;
                f32x4 v = acc[ni][mi];
                f32x4 o;
                if (gn < ODIM) {
                    #pragma unroll
                    for (int j = 0; j < 4; ++j) {
                        float e = v[j] + bv[j];
                        o[j] = msk ? __builtin_nanf("") : e;
                    }
                    *(f32x4*)&outv[token * ODIM + gn] = o;
                } else {
                    #pragma unroll
                    for (int j = 0; j < 4; ++j) {
                        float e = v[j] + bv[j];
                        float sp = (e > 20.f) ? e : log1pf(expf(e));
                        float var = 0.01f + 0.99f * sp;
                        o[j] = msk ? __builtin_nanf("") : var;
                    }
                    *(f32x4*)&outv[VAROFF + token * ODIM + (gn - ODIM)] = o;
                }
            }
        }
    }
}

extern "C" void kernel_launch(void* const* d_in, const int* in_sizes, int n_in,
                              void* d_out, int out_size, void* d_ws, size_t ws_size,
                              hipStream_t stream)
{
    const float* x     = (const float*)d_in[0];   // (8192,16,256)
    const unsigned char* mask = (const unsigned char*)d_in[1]; // (8192,16) bool (all false)
    const float* W_in  = (const float*)d_in[2];   // (16,512,256)
    const float* b_in  = (const float*)d_in[3];   // (16,512)
    const float* W1    = (const float*)d_in[4];   // (1024,512)
    const float* b1    = (const float*)d_in[5];
    const float* W2    = (const float*)d_in[6];   // (1024,1024)
    const float* b2    = (const float*)d_in[7];
    const float* W3    = (const float*)d_in[8];   // (512,1024)
    const float* b3    = (const float*)d_in[9];
    const float* W_out = (const float*)d_in[10];  // (16,256,512)
    const float* b_out = (const float*)d_in[11];  // (16,256)
    float* out = (float*)d_out;

    // ws carve (uint16 elems): weights | xb | bufA | bufB, chunked over n to fit ws_size.
    uint16_t* ws   = (uint16_t*)d_ws;
    uint16_t* Wib  = ws;                    // 2,097,152
    uint16_t* W1b  = Wib + 2097152;         //   524,288
    uint16_t* W2b  = W1b + 524288;          // 1,048,576
    uint16_t* W3b  = W2b + 1048576;         //   524,288
    uint16_t* Wob  = W3b + 524288;          // 2,097,152
    uint16_t* base = Wob + 2097152;         // = ws + 6,291,456

    // pick largest NC (power of two, >=128) with
    //   bytes = 12,582,912 + NC*(4096+16384+16384)*2 <= ws_size
    long long NC = 8192;
    while (NC > 128 && 12582912LL + NC * 73728LL > (long long)ws_size) NC >>= 1;

    uint16_t* xb   = base;                  // NC*4096
    uint16_t* bufA = xb   + NC * 4096;      // NC*16384 (h0, h2)
    uint16_t* bufB = bufA + NC * 16384;     // NC*16384 (h1, h3)

    auto conv = [&](const float* src, uint16_t* dst, long long n) {
        long long n4 = n >> 2;
        convert_f32_bf16<<<dim3((unsigned)((n4 + 255) / 256)), dim3(256), 0, stream>>>(src, dst, (int)n4);
    };
    conv(W_in,  Wib, 2097152);
    conv(W1,    W1b, 524288);
    conv(W2,    W2b, 1048576);
    conv(W3,    W3b, 524288);
    conv(W_out, Wob, 2097152);

    const int nChunks = (int)(NTOK / NC);
    for (int c = 0; c < nChunks; ++c) {
        const long long nb = (long long)c * NC;           // n-offset of this chunk
        // x chunk -> bf16
        conv(x + nb * PDIM * 256, xb, NC * PDIM * 256);
        // L_in: per-p (NC x 512 x 256); h0 token-major (row stride 512)
        gemm_bt<0><<<dim3((unsigned)(NC / 128), 4, 16), 256, 0, stream>>>(
            xb, 4096, 256, Wib, 256, 131072, b_in, 512,
            bufA, 8192, 512, 256, nullptr, nullptr);
        // L1: (NC*16) x 1024 x 512, relu
        gemm_bt<1><<<dim3((unsigned)(NC / 8), 8, 1), 256, 0, stream>>>(
            bufA, 512, 0, W1b, 512, 0, b1, 0,
            bufB, 1024, 0, 512, nullptr, nullptr);
        // L2: (NC*16) x 1024 x 1024, relu
        gemm_bt<1><<<dim3((unsigned)(NC / 8), 8, 1), 256, 0, stream>>>(
            bufB, 1024, 0, W2b, 1024, 0, b2, 0,
            bufA, 1024, 0, 1024, nullptr, nullptr);
        // L3: (NC*16) x 512 x 1024, relu
        gemm_bt<1><<<dim3((unsigned)(NC / 8), 4, 1), 256, 0, stream>>>(
            bufA, 1024, 0, W3b, 1024, 0, b3, 0,
            bufB, 512, 0, 1024, nullptr, nullptr);
        // L_out: per-p (NC x 256 x 512) -> fused mu/var/softplus/mask to d_out
        gemm_bt<2><<<dim3((unsigned)(NC / 128), 2, 16), 256, 0, stream>>>(
            bufB, 8192, 512, Wob, 512, 131072, b_out, 256,
            nullptr, 0, 0, 512,
            mask + nb * PDIM, out + nb * PDIM * ODIM);
    }
}

// Round 3
// 1289.581 us; speedup vs baseline: 1.2443x; 1.2443x over previous
//
#include <hip/hip_runtime.h>
#include <stdint.h>

typedef __attribute__((ext_vector_type(8))) short short8;
typedef __attribute__((ext_vector_type(4))) float f32x4;
typedef __attribute__((ext_vector_type(4))) unsigned short u16x4;

#define NTOK 8192
#define PDIM 16
#define ODIM 128

__device__ __forceinline__ uint16_t f2bf(float f) {
    uint32_t u = __builtin_bit_cast(uint32_t, f);
    u += 0x7FFFu + ((u >> 16) & 1u);   // RNE
    return (uint16_t)(u >> 16);
}

__global__ void convert_f32_bf16(const float* __restrict__ in, uint16_t* __restrict__ out, int n4) {
    int i = blockIdx.x * blockDim.x + threadIdx.x;
    if (i >= n4) return;
    f32x4 v = ((const f32x4*)in)[i];
    u16x4 o;
    o[0] = f2bf(v[0]); o[1] = f2bf(v[1]); o[2] = f2bf(v[2]); o[3] = f2bf(v[3]);
    ((u16x4*)out)[i] = o;
}

// C[m,n] = sum_k A[m,k] * B[n,k]  (B^T / weight-row layout), bf16 in, fp32 accum.
// BM=128, BN=256, BK=64. 512 threads = 8 waves (2 m-groups x 4 n-groups),
// per-wave 64x64 output. 3 K-tile LDS buffers, counted vmcnt(6) + 1 raw
// s_barrier per K-tile (pipelined staging stays in flight across barriers).
// LDS layout XOR-swizzled (chunk ^= row&7): pre-swizzled global source for
// global_load_lds (linear dest) + same XOR on ds_read addresses.
// EPI 0: +bias, bf16.  EPI 1: +bias+relu, bf16.  EPI 2: mu/var/softplus/mask -> f32.
template<int EPI>
__global__ __launch_bounds__(512, 1)
void gemm3(const uint16_t* __restrict__ A, int lda, long long Abatch,
           const uint16_t* __restrict__ B, int ldb, long long Bbatch,
           const float* __restrict__ bias, int biasBatch,
           uint16_t* __restrict__ C, int ldc, long long Cbatch,
           int K, int gridN, int gridM,
           const unsigned char* __restrict__ mask,
           float* __restrict__ outv)
{
    __shared__ uint16_t lds[73728];   // 3 x (A 8192 + B 16384) elems = 144 KB

    const int tid  = threadIdx.x;
    const int wid  = tid >> 6;
    const int lane = tid & 63;
    const int l15  = lane & 15;
    const int kg   = lane >> 4;
    const int wm   = wid >> 2;   // 0..1
    const int wn   = wid & 3;    // 0..3

    // XCD-chunked swizzle (launcher guarantees nwg % 8 == 0), n-fastest decode
    const int nwg = (int)gridDim.x;
    int id = (int)blockIdx.x;
    id = (id & 7) * (nwg >> 3) + (id >> 3);
    const int n_blk = id % gridN;
    const int rest  = id / gridN;
    const int m_blk = rest % gridM;
    const int p     = rest / gridM;

    const int m0 = m_blk * 128;
    const int n0 = n_blk * 256;

    const uint16_t* Ap = A + (long long)p * Abatch;
    const uint16_t* Bp = B + (long long)p * Bbatch;

    // ---- staging addresses: linear LDS dest, XOR-pre-swizzled global src ----
    const int c3 = tid >> 3;                        // row within 64-row quantum
    const int k8 = ((tid & 7) ^ (c3 & 7)) * 8;      // swizzled k-chunk (elems)
    const uint16_t* sA0 = Ap + (long long)(m0 + c3) * lda + k8;
    const uint16_t* sA1 = sA0 + (long long)64 * lda;
    const uint16_t* sB0 = Bp + (long long)(n0 + c3) * ldb + k8;
    const uint16_t* sB1 = sB0 + (long long)64 * ldb;
    const uint16_t* sB2 = sB0 + (long long)128 * ldb;
    const uint16_t* sB3 = sB0 + (long long)192 * ldb;
    const int dW = wid * 512;                       // per-wave LDS slice (elems)

#define GLL(SRC, DST) __builtin_amdgcn_global_load_lds( \
        (const __attribute__((address_space(1))) void*)(SRC), \
        (__attribute__((address_space(3))) void*)(&lds[DST]), 16, 0, 0)

    auto stage = [&](int kt, int bb) {
        const int o = kt * 64;
        GLL(sA0 + o, bb + dW);
        GLL(sA1 + o, bb + 4096 + dW);
        GLL(sB0 + o, bb + 8192 + dW);
        GLL(sB1 + o, bb + 12288 + dW);
        GLL(sB2 + o, bb + 16384 + dW);
        GLL(sB3 + o, bb + 20480 + dW);
    };

    // ---- fragment read offsets (same XOR swizzle) ----
    const int cs0 = (kg ^ (l15 & 7)) * 8;           // ks=0 chunk
    const int cs1 = ((kg + 4) ^ (l15 & 7)) * 8;     // ks=1 chunk
    const int rX = (wm * 64 + l15) * 64;            // activations (A region)
    const int rW = 8192 + (wn * 64 + l15) * 64;     // weights (B region)

    f32x4 acc[4][4];
    #pragma unroll
    for (int i = 0; i < 4; ++i)
        #pragma unroll
        for (int j = 0; j < 4; ++j)
            acc[i][j] = (f32x4){0.f, 0.f, 0.f, 0.f};

    const int NT = K >> 6;
    stage(0, 0);
    stage(1, 24576);
    asm volatile("s_waitcnt vmcnt(6)\ns_barrier" ::: "memory");

    int cur = 0;
    for (int t = 0; t < NT; ++t) {
        const int bb = cur * 24576;
        short8 xf[4][2], wfa[2][2], wfb[2][2];
        #pragma unroll
        for (int mi = 0; mi < 4; ++mi) {
            xf[mi][0] = *(const short8*)&lds[bb + rX + mi * 1024 + cs0];
            xf[mi][1] = *(const short8*)&lds[bb + rX + mi * 1024 + cs1];
        }
        #pragma unroll
        for (int ni = 0; ni < 2; ++ni) {
            wfa[ni][0] = *(const short8*)&lds[bb + rW + ni * 1024 + cs0];
            wfa[ni][1] = *(const short8*)&lds[bb + rW + ni * 1024 + cs1];
        }
        const bool more = (t + 2 < NT);
        if (more) stage(t + 2, (cur == 0 ? 2 : cur - 1) * 24576);
        #pragma unroll
        for (int ni = 0; ni < 2; ++ni)
            #pragma unroll
            for (int mi = 0; mi < 4; ++mi) {
                acc[ni][mi] = __builtin_amdgcn_mfma_f32_16x16x32_bf16(wfa[ni][0], xf[mi][0], acc[ni][mi], 0, 0, 0);
                acc[ni][mi] = __builtin_amdgcn_mfma_f32_16x16x32_bf16(wfa[ni][1], xf[mi][1], acc[ni][mi], 0, 0, 0);
            }
        #pragma unroll
        for (int ni = 0; ni < 2; ++ni) {
            wfb[ni][0] = *(const short8*)&lds[bb + rW + (ni + 2) * 1024 + cs0];
            wfb[ni][1] = *(const short8*)&lds[bb + rW + (ni + 2) * 1024 + cs1];
        }
        #pragma unroll
        for (int ni = 0; ni < 2; ++ni)
            #pragma unroll
            for (int mi = 0; mi < 4; ++mi) {
                acc[ni + 2][mi] = __builtin_amdgcn_mfma_f32_16x16x32_bf16(wfb[ni][0], xf[mi][0], acc[ni + 2][mi], 0, 0, 0);
                acc[ni + 2][mi] = __builtin_amdgcn_mfma_f32_16x16x32_bf16(wfb[ni][1], xf[mi][1], acc[ni + 2][mi], 0, 0, 0);
            }
        if (more) asm volatile("s_waitcnt vmcnt(6) lgkmcnt(0)\ns_barrier" ::: "memory");
        else      asm volatile("s_waitcnt vmcnt(0) lgkmcnt(0)\ns_barrier" ::: "memory");
        cur = (cur == 2) ? 0 : cur + 1;
    }
#undef GLL

    // epilogue: lane holds m = l15, n = base + kg*4 + j (j contiguous)
    if (EPI == 0 || EPI == 1) {
        uint16_t* Cp = C + (long long)p * Cbatch;
        const float* biasp = bias + (long long)p * biasBatch;
        #pragma unroll
        for (int ni = 0; ni < 4; ++ni) {
            const int gn = n0 + wn * 64 + ni * 16 + kg * 4;
            const f32x4 bv = *(const f32x4*)&biasp[gn];
            #pragma unroll
            for (int mi = 0; mi < 4; ++mi) {
                const int gm = m0 + wm * 64 + mi * 16 + l15;
                f32x4 v = acc[ni][mi];
                u16x4 o;
                #pragma unroll
                for (int j = 0; j < 4; ++j) {
                    float e = v[j] + bv[j];
                    if (EPI == 1) e = fmaxf(e, 0.f);
                    o[j] = f2bf(e);
                }
                *(u16x4*)&Cp[(long long)gm * ldc + gn] = o;
            }
        }
    } else {
        const long long VAROFF = (long long)NTOK * PDIM * ODIM;
        const float* biasp = bias + (long long)p * biasBatch;
        #pragma unroll
        for (int ni = 0; ni < 4; ++ni) {
            const int gn = n0 + wn * 64 + ni * 16 + kg * 4;
            const f32x4 bv = *(const f32x4*)&biasp[gn];
            #pragma unroll
            for (int mi = 0; mi < 4; ++mi) {
                const int gm = m0 + wm * 64 + mi * 16 + l15;     // local sample idx
                const long long token = (long long)gm * PDIM + p;
                const bool msk = mask[token] != 0;
                f32x4 v = acc[ni][mi];
                f32x4 o;
                if (gn < ODIM) {
                    #pragma unroll
                    for (int j = 0; j < 4; ++j) {
                        float e = v[j] + bv[j];
                        o[j] = msk ? __builtin_nanf("") : e;
                    }
                    *(f32x4*)&outv[token * ODIM + gn] = o;
                } else {
                    #pragma unroll
                    for (int j = 0; j < 4; ++j) {
                        float e = v[j] + bv[j];
                        float sp = (e > 20.f) ? e : log1pf(expf(e));
                        float var = 0.01f + 0.99f * sp;
                        o[j] = msk ? __builtin_nanf("") : var;
                    }
                    *(f32x4*)&outv[VAROFF + token * ODIM + (gn - ODIM)] = o;
                }
            }
        }
    }
}

extern "C" void kernel_launch(void* const* d_in, const int* in_sizes, int n_in,
                              void* d_out, int out_size, void* d_ws, size_t ws_size,
                              hipStream_t stream)
{
    const float* x     = (const float*)d_in[0];   // (8192,16,256)
    const unsigned char* mask = (const unsigned char*)d_in[1]; // (8192,16) bool
    const float* W_in  = (const float*)d_in[2];   // (16,512,256)
    const float* b_in  = (const float*)d_in[3];   // (16,512)
    const float* W1    = (const float*)d_in[4];   // (1024,512)
    const float* b1    = (const float*)d_in[5];
    const float* W2    = (const float*)d_in[6];   // (1024,1024)
    const float* b2    = (const float*)d_in[7];
    const float* W3    = (const float*)d_in[8];   // (512,1024)
    const float* b3    = (const float*)d_in[9];
    const float* W_out = (const float*)d_in[10];  // (16,256,512)
    const float* b_out = (const float*)d_in[11];  // (16,256)
    float* out = (float*)d_out;

    // ws carve (uint16 elems): weights | xb | bufA | bufB, chunked over n to fit.
    uint16_t* ws   = (uint16_t*)d_ws;
    uint16_t* Wib  = ws;                    // 2,097,152
    uint16_t* W1b  = Wib + 2097152;         //   524,288
    uint16_t* W2b  = W1b + 524288;          // 1,048,576
    uint16_t* W3b  = W2b + 1048576;         //   524,288
    uint16_t* Wob  = W3b + 524288;          // 2,097,152
    uint16_t* base = Wob + 2097152;         // = ws + 6,291,456

    long long NC = 8192;
    while (NC > 128 && 12582912LL + NC * 73728LL > (long long)ws_size) NC >>= 1;

    uint16_t* xb   = base;                  // NC*4096
    uint16_t* bufA = xb   + NC * 4096;      // NC*16384 (h0, h2)
    uint16_t* bufB = bufA + NC * 16384;     // NC*16384 (h1, h3)

    auto conv = [&](const float* src, uint16_t* dst, long long n) {
        long long n4 = n >> 2;
        convert_f32_bf16<<<dim3((unsigned)((n4 + 255) / 256)), dim3(256), 0, stream>>>(src, dst, (int)n4);
    };
    conv(W_in,  Wib, 2097152);
    conv(W1,    W1b, 524288);
    conv(W2,    W2b, 1048576);
    conv(W3,    W3b, 524288);
    conv(W_out, Wob, 2097152);

    const int nChunks = (int)(NTOK / NC);
    for (int c = 0; c < nChunks; ++c) {
        const long long nb = (long long)c * NC;
        const int NB = (int)(NC / 128);
        conv(x + nb * PDIM * 256, xb, NC * PDIM * 256);
        // L_in: per-p (NC x 512 x 256); h0 token-major (row stride 512)
        gemm3<0><<<dim3((unsigned)(2 * NB * 16)), 512, 0, stream>>>(
            xb, 4096, 256, Wib, 256, 131072, b_in, 512,
            bufA, 8192, 512, 256, 2, NB, nullptr, nullptr);
        // L1: (NC*16) x 1024 x 512, relu
        gemm3<1><<<dim3((unsigned)(4 * NB * 16)), 512, 0, stream>>>(
            bufA, 512, 0, W1b, 512, 0, b1, 0,
            bufB, 1024, 0, 512, 4, NB * 16, nullptr, nullptr);
        // L2: (NC*16) x 1024 x 1024, relu
        gemm3<1><<<dim3((unsigned)(4 * NB * 16)), 512, 0, stream>>>(
            bufB, 1024, 0, W2b, 1024, 0, b2, 0,
            bufA, 1024, 0, 1024, 4, NB * 16, nullptr, nullptr);
        // L3: (NC*16) x 512 x 1024, relu
        gemm3<1><<<dim3((unsigned)(2 * NB * 16)), 512, 0, stream>>>(
            bufA, 1024, 0, W3b, 1024, 0, b3, 0,
            bufB, 512, 0, 1024, 2, NB * 16, nullptr, nullptr);
        // L_out: per-p (NC x 256 x 512) -> fused mu/var/softplus/mask to d_out
        gemm3<2><<<dim3((unsigned)(1 * NB * 16)), 512, 0, stream>>>(
            bufB, 8192, 512, Wob, 512, 131072, b_out, 256,
            nullptr, 0, 0, 512, 1, NB,
            mask + nb * PDIM, out + nb * PDIM * ODIM);
    }
}

// Round 5
// 1248.213 us; speedup vs baseline: 1.2855x; 1.0331x over previous
//
#include <hip/hip_runtime.h>
#include <stdint.h>

typedef __attribute__((ext_vector_type(8))) short short8;
typedef __attribute__((ext_vector_type(4))) float f32x4;
typedef __attribute__((ext_vector_type(4))) unsigned short u16x4;

#define NTOK 8192
#define PDIM 16
#define ODIM 128

__device__ __forceinline__ uint16_t f2bf(float f) {
    uint32_t u = __builtin_bit_cast(uint32_t, f);
    u += 0x7FFFu + ((u >> 16) & 1u);   // RNE
    return (uint16_t)(u >> 16);
}

__global__ void convert_f32_bf16(const float* __restrict__ in, uint16_t* __restrict__ out, int n4) {
    int i = blockIdx.x * blockDim.x + threadIdx.x;
    if (i >= n4) return;
    f32x4 v = ((const f32x4*)in)[i];
    u16x4 o;
    o[0] = f2bf(v[0]); o[1] = f2bf(v[1]); o[2] = f2bf(v[2]); o[3] = f2bf(v[3]);
    ((u16x4*)out)[i] = o;
}

// one launch converting up to 6 f32->bf16 segments (x + 5 weight tensors)
__global__ void convert_multi(
    const float* __restrict__ s0, uint16_t* __restrict__ d0, long long e0,
    const float* __restrict__ s1, uint16_t* __restrict__ d1, long long e1,
    const float* __restrict__ s2, uint16_t* __restrict__ d2, long long e2,
    const float* __restrict__ s3, uint16_t* __restrict__ d3, long long e3,
    const float* __restrict__ s4, uint16_t* __restrict__ d4, long long e4,
    const float* __restrict__ s5, uint16_t* __restrict__ d5, long long e5)
{
    long long i = (long long)blockIdx.x * blockDim.x + threadIdx.x;
    if (i >= e5) return;
    const float* s; uint16_t* d; long long b;
    if      (i < e0) { s = s0; d = d0; b = 0;  }
    else if (i < e1) { s = s1; d = d1; b = e0; }
    else if (i < e2) { s = s2; d = d2; b = e1; }
    else if (i < e3) { s = s3; d = d3; b = e2; }
    else if (i < e4) { s = s4; d = d4; b = e3; }
    else             { s = s5; d = d5; b = e4; }
    const long long j = i - b;
    f32x4 v = ((const f32x4*)s)[j];
    u16x4 o;
    o[0] = f2bf(v[0]); o[1] = f2bf(v[1]); o[2] = f2bf(v[2]); o[3] = f2bf(v[3]);
    ((u16x4*)d)[j] = o;
}

// C[m,n] = sum_k A[m,k] * B[n,k]  (B^T / weight-row layout), bf16 in, fp32 accum.
// BM=128, BN=256, BK=64. 512 threads = 8 waves (2m x 4n), per-wave 64x64 out.
// 3 K-tile LDS buffers, counted vmcnt(6) + 1 raw s_barrier per K-tile.
// T2 XOR swizzle: pre-swizzled global source (linear LDS dest for
// global_load_lds) + same XOR on ds_read addresses.
// EPI 0: +bias, bf16.  EPI 1: +bias+relu, bf16.  EPI 2: mu/var/softplus/mask -> f32.
template<int EPI>
__device__ __forceinline__
void gemm_body(const uint16_t* __restrict__ A, int lda, long long Abatch,
               const uint16_t* __restrict__ B, int ldb, long long Bbatch,
               const float* __restrict__ bias, int biasBatch,
               uint16_t* __restrict__ C, int ldc, long long Cbatch,
               int K, int gridN, int gridM,
               const unsigned char* __restrict__ mask,
               float* __restrict__ outv)
{
    __shared__ uint16_t lds[73728];   // 3 x (A 8192 + B 16384) elems = 144 KB

    const int tid  = threadIdx.x;
    const int wid  = tid >> 6;
    const int lane = tid & 63;
    const int l15  = lane & 15;
    const int kg   = lane >> 4;
    const int wm   = wid >> 2;   // 0..1
    const int wn   = wid & 3;    // 0..3

    // XCD-chunked swizzle (launcher guarantees nwg % 8 == 0), n-fastest decode
    const int nwg = (int)gridDim.x;
    int id = (int)blockIdx.x;
    id = (id & 7) * (nwg >> 3) + (id >> 3);
    const int n_blk = id % gridN;
    const int rest  = id / gridN;
    const int m_blk = rest % gridM;
    const int p     = rest / gridM;

    const int m0 = m_blk * 128;
    const int n0 = n_blk * 256;

    const uint16_t* Ap = A + (long long)p * Abatch;
    const uint16_t* Bp = B + (long long)p * Bbatch;

    // ---- staging addresses: linear LDS dest, XOR-pre-swizzled global src ----
    const int c3 = tid >> 3;                        // row within 64-row quantum
    const int k8 = ((tid & 7) ^ (c3 & 7)) * 8;      // swizzled k-chunk (elems)
    const uint16_t* sA0 = Ap + (long long)(m0 + c3) * lda + k8;
    const uint16_t* sA1 = sA0 + (long long)64 * lda;
    const uint16_t* sB0 = Bp + (long long)(n0 + c3) * ldb + k8;
    const uint16_t* sB1 = sB0 + (long long)64 * ldb;
    const uint16_t* sB2 = sB0 + (long long)128 * ldb;
    const uint16_t* sB3 = sB0 + (long long)192 * ldb;
    const int dW = wid * 512;                       // per-wave LDS slice (elems)

#define GLL(SRC, DST) __builtin_amdgcn_global_load_lds( \
        (const __attribute__((address_space(1))) void*)(SRC), \
        (__attribute__((address_space(3))) void*)(&lds[DST]), 16, 0, 0)

    auto stage = [&](int kt, int bb) {
        const int o = kt * 64;
        GLL(sA0 + o, bb + dW);
        GLL(sA1 + o, bb + 4096 + dW);
        GLL(sB0 + o, bb + 8192 + dW);
        GLL(sB1 + o, bb + 12288 + dW);
        GLL(sB2 + o, bb + 16384 + dW);
        GLL(sB3 + o, bb + 20480 + dW);
    };

    // ---- fragment read offsets (same XOR swizzle) ----
    const int cs0 = (kg ^ (l15 & 7)) * 8;           // ks=0 chunk
    const int cs1 = ((kg + 4) ^ (l15 & 7)) * 8;     // ks=1 chunk
    const int rX = (wm * 64 + l15) * 64;            // activations (A region)
    const int rW = 8192 + (wn * 64 + l15) * 64;     // weights (B region)

    f32x4 acc[4][4];
    #pragma unroll
    for (int i = 0; i < 4; ++i)
        #pragma unroll
        for (int j = 0; j < 4; ++j)
            acc[i][j] = (f32x4){0.f, 0.f, 0.f, 0.f};

    const int NT = K >> 6;
    stage(0, 0);
    stage(1, 24576);
    asm volatile("s_waitcnt vmcnt(6)\ns_barrier" ::: "memory");

    int cur = 0;
    for (int t = 0; t < NT; ++t) {
        const int bb = cur * 24576;
        const bool more = (t + 2 < NT);
        if (more) stage(t + 2, (cur == 0 ? 2 : cur - 1) * 24576);   // issue-early (T3)
        short8 xf[4][2], wfa[2][2], wfb[2][2];
        #pragma unroll
        for (int mi = 0; mi < 4; ++mi) {
            xf[mi][0] = *(const short8*)&lds[bb + rX + mi * 1024 + cs0];
            xf[mi][1] = *(const short8*)&lds[bb + rX + mi * 1024 + cs1];
        }
        #pragma unroll
        for (int ni = 0; ni < 2; ++ni) {
            wfa[ni][0] = *(const short8*)&lds[bb + rW + ni * 1024 + cs0];
            wfa[ni][1] = *(const short8*)&lds[bb + rW + ni * 1024 + cs1];
        }
        __builtin_amdgcn_s_setprio(1);
        #pragma unroll
        for (int ni = 0; ni < 2; ++ni)
            #pragma unroll
            for (int mi = 0; mi < 4; ++mi) {
                acc[ni][mi] = __builtin_amdgcn_mfma_f32_16x16x32_bf16(wfa[ni][0], xf[mi][0], acc[ni][mi], 0, 0, 0);
                acc[ni][mi] = __builtin_amdgcn_mfma_f32_16x16x32_bf16(wfa[ni][1], xf[mi][1], acc[ni][mi], 0, 0, 0);
            }
        __builtin_amdgcn_s_setprio(0);
        #pragma unroll
        for (int ni = 0; ni < 2; ++ni) {
            wfb[ni][0] = *(const short8*)&lds[bb + rW + (ni + 2) * 1024 + cs0];
            wfb[ni][1] = *(const short8*)&lds[bb + rW + (ni + 2) * 1024 + cs1];
        }
        __builtin_amdgcn_s_setprio(1);
        #pragma unroll
        for (int ni = 0; ni < 2; ++ni)
            #pragma unroll
            for (int mi = 0; mi < 4; ++mi) {
                acc[ni + 2][mi] = __builtin_amdgcn_mfma_f32_16x16x32_bf16(wfb[ni][0], xf[mi][0], acc[ni + 2][mi], 0, 0, 0);
                acc[ni + 2][mi] = __builtin_amdgcn_mfma_f32_16x16x32_bf16(wfb[ni][1], xf[mi][1], acc[ni + 2][mi], 0, 0, 0);
            }
        __builtin_amdgcn_s_setprio(0);
        if (more) asm volatile("s_waitcnt vmcnt(6) lgkmcnt(0)\ns_barrier" ::: "memory");
        else      asm volatile("s_waitcnt vmcnt(0) lgkmcnt(0)\ns_barrier" ::: "memory");
        cur = (cur == 2) ? 0 : cur + 1;
    }
#undef GLL

    // epilogue: lane holds m = l15, n = base + kg*4 + j (j contiguous)
    if (EPI == 0 || EPI == 1) {
        uint16_t* Cp = C + (long long)p * Cbatch;
        const float* biasp = bias + (long long)p * biasBatch;
        #pragma unroll
        for (int ni = 0; ni < 4; ++ni) {
            const int gn = n0 + wn * 64 + ni * 16 + kg * 4;
            const f32x4 bv = *(const f32x4*)&biasp[gn];
            #pragma unroll
            for (int mi = 0; mi < 4; ++mi) {
                const int gm = m0 + wm * 64 + mi * 16 + l15;
                f32x4 v = acc[ni][mi];
                u16x4 o;
                #pragma unroll
                for (int j = 0; j < 4; ++j) {
                    float e = v[j] + bv[j];
                    if (EPI == 1) e = fmaxf(e, 0.f);
                    o[j] = f2bf(e);
                }
                *(u16x4*)&Cp[(long long)gm * ldc + gn] = o;
            }
        }
    } else {
        const long long VAROFF = (long long)NTOK * PDIM * ODIM;
        const float* biasp = bias + (long long)p * biasBatch;
        #pragma unroll
        for (int ni = 0; ni < 4; ++ni) {
            const int gn = n0 + wn * 64 + ni * 16 + kg * 4;
            const f32x4 bv = *(const f32x4*)&biasp[gn];
            #pragma unroll
            for (int mi = 0; mi < 4; ++mi) {
                const int gm = m0 + wm * 64 + mi * 16 + l15;     // local sample idx
                const long long token = (long long)gm * PDIM + p;
                const bool msk = mask[token] != 0;
                f32x4 v = acc[ni][mi];
                f32x4 o;
                if (gn < ODIM) {
                    #pragma unroll
                    for (int j = 0; j < 4; ++j) {
                        float e = v[j] + bv[j];
                        o[j] = msk ? __builtin_nanf("") : e;
                    }
                    *(f32x4*)&outv[token * ODIM + gn] = o;
                } else {
                    #pragma unroll
                    for (int j = 0; j < 4; ++j) {
                        float e = v[j] + bv[j];
                        float sp = (e > 20.f) ? e : log1pf(expf(e));
                        float var = 0.01f + 0.99f * sp;
                        o[j] = msk ? __builtin_nanf("") : var;
                    }
                    *(f32x4*)&outv[VAROFF + token * ODIM + (gn - ODIM)] = o;
                }
            }
        }
    }
}

#define GEMM_PARAMS const uint16_t* A, int lda, long long Abatch, \
                    const uint16_t* B, int ldb, long long Bbatch, \
                    const float* bias, int biasBatch, \
                    uint16_t* C, int ldc, long long Cbatch, \
                    int K, int gridN, int gridM, \
                    const unsigned char* mask, float* outv
#define GEMM_ARGS A, lda, Abatch, B, ldb, Bbatch, bias, biasBatch, C, ldc, Cbatch, \
                  K, gridN, gridM, mask, outv

// distinct names per layer for rocprof visibility
__global__ __launch_bounds__(512, 1) void g_Lin (GEMM_PARAMS) { gemm_body<0>(GEMM_ARGS); }
__global__ __launch_bounds__(512, 1) void g_L1  (GEMM_PARAMS) { gemm_body<1>(GEMM_ARGS); }
__global__ __launch_bounds__(512, 1) void g_L2  (GEMM_PARAMS) { gemm_body<1>(GEMM_ARGS); }
__global__ __launch_bounds__(512, 1) void g_L3  (GEMM_PARAMS) { gemm_body<1>(GEMM_ARGS); }
__global__ __launch_bounds__(512, 1) void g_Lout(GEMM_PARAMS) { gemm_body<2>(GEMM_ARGS); }

extern "C" void kernel_launch(void* const* d_in, const int* in_sizes, int n_in,
                              void* d_out, int out_size, void* d_ws, size_t ws_size,
                              hipStream_t stream)
{
    const float* x     = (const float*)d_in[0];   // (8192,16,256)
    const unsigned char* mask = (const unsigned char*)d_in[1]; // (8192,16) bool
    const float* W_in  = (const float*)d_in[2];   // (16,512,256)
    const float* b_in  = (const float*)d_in[3];   // (16,512)
    const float* W1    = (const float*)d_in[4];   // (1024,512)
    const float* b1    = (const float*)d_in[5];
    const float* W2    = (const float*)d_in[6];   // (1024,1024)
    const float* b2    = (const float*)d_in[7];
    const float* W3    = (const float*)d_in[8];   // (512,1024)
    const float* b3    = (const float*)d_in[9];
    const float* W_out = (const float*)d_in[10];  // (16,256,512)
    const float* b_out = (const float*)d_in[11];  // (16,256)
    float* out = (float*)d_out;

    // ws carve (uint16 elems): weights | xb | bufA | bufB, chunked over n to fit.
    uint16_t* ws   = (uint16_t*)d_ws;
    uint16_t* Wib  = ws;                    // 2,097,152
    uint16_t* W1b  = Wib + 2097152;         //   524,288
    uint16_t* W2b  = W1b + 524288;          // 1,048,576
    uint16_t* W3b  = W2b + 1048576;         //   524,288
    uint16_t* Wob  = W3b + 524288;          // 2,097,152
    uint16_t* base = Wob + 2097152;         // = ws + 6,291,456

    long long NC = 8192;
    while (NC > 128 && 12582912LL + NC * 73728LL > (long long)ws_size) NC >>= 1;

    uint16_t* xb   = base;                  // NC*4096
    uint16_t* bufA = xb   + NC * 4096;      // NC*16384 (h0, h2)
    uint16_t* bufB = bufA + NC * 16384;     // NC*16384 (h1, h3)

    // ---- conversions ----
    if (NC == 8192) {
        // single merged launch: 5 weights + all of x (vec4 units)
        const long long e0 = 2097152 / 4;                 // W_in
        const long long e1 = e0 + 524288 / 4;             // W1
        const long long e2 = e1 + 1048576 / 4;            // W2
        const long long e3 = e2 + 524288 / 4;             // W3
        const long long e4 = e3 + 2097152 / 4;            // W_out
        const long long e5 = e4 + 33554432 / 4;           // x
        convert_multi<<<dim3((unsigned)((e5 + 255) / 256)), dim3(256), 0, stream>>>(
            W_in, Wib, e0, W1, W1b, e1, W2, W2b, e2,
            W3, W3b, e3, W_out, Wob, e4, x, xb, e5);
    } else {
        const long long e0 = 2097152 / 4;
        const long long e1 = e0 + 524288 / 4;
        const long long e2 = e1 + 1048576 / 4;
        const long long e3 = e2 + 524288 / 4;
        const long long e4 = e3 + 2097152 / 4;
        convert_multi<<<dim3((unsigned)((e4 + 255) / 256)), dim3(256), 0, stream>>>(
            W_in, Wib, e0, W1, W1b, e1, W2, W2b, e2,
            W3, W3b, e3, W_out, Wob, e4, W_out, Wob, e4);
    }

    const int nChunks = (int)(NTOK / NC);
    for (int c = 0; c < nChunks; ++c) {
        const long long nb = (long long)c * NC;
        const int NB = (int)(NC / 128);
        if (NC != 8192) {
            long long n4 = (NC * PDIM * 256) >> 2;
            convert_f32_bf16<<<dim3((unsigned)((n4 + 255) / 256)), dim3(256), 0, stream>>>(
                x + nb * PDIM * 256, xb, (int)n4);
        }
        // L_in: per-p (NC x 512 x 256); h0 token-major (row stride 512)
        g_Lin<<<dim3((unsigned)(2 * NB * 16)), 512, 0, stream>>>(
            xb, 4096, 256, Wib, 256, 131072, b_in, 512,
            bufA, 8192, 512, 256, 2, NB, nullptr, nullptr);
        // L1: (NC*16) x 1024 x 512, relu
        g_L1<<<dim3((unsigned)(4 * NB * 16)), 512, 0, stream>>>(
            bufA, 512, 0, W1b, 512, 0, b1, 0,
            bufB, 1024, 0, 512, 4, NB * 16, nullptr, nullptr);
        // L2: (NC*16) x 1024 x 1024, relu
        g_L2<<<dim3((unsigned)(4 * NB * 16)), 512, 0, stream>>>(
            bufB, 1024, 0, W2b, 1024, 0, b2, 0,
            bufA, 1024, 0, 1024, 4, NB * 16, nullptr, nullptr);
        // L3: (NC*16) x 512 x 1024, relu
        g_L3<<<dim3((unsigned)(2 * NB * 16)), 512, 0, stream>>>(
            bufA, 1024, 0, W3b, 1024, 0, b3, 0,
            bufB, 512, 0, 1024, 2, NB * 16, nullptr, nullptr);
        // L_out: per-p (NC x 256 x 512) -> fused mu/var/softplus/mask to d_out
        g_Lout<<<dim3((unsigned)(1 * NB * 16)), 512, 0, stream>>>(
            bufB, 8192, 512, Wob, 512, 131072, b_out, 256,
            nullptr, 0, 0, 512, 1, NB,
            mask + nb * PDIM, out + nb * PDIM * ODIM);
    }
}